// Round 18
// baseline (772.192 us; speedup 1.0000x reference)
//
#include <hip/hip_runtime.h>
#include <hip/hip_bf16.h>

// Problem constants
#define MROW 8192   // BATCH
#define DIMK 4096   // DIM (= K of both GEMMs)
#define NCOL 4096   // N_HEADS*HIDDEN = DIM
#define HID  256
#define NH   16
#define SEQL 4096

// GEMM (R17 structure, 32x32x16 MFMA): 256x256 tile, BK=32, 16 waves
// (4M x 4N, wave-tile 64x64 = 2x2 frags of 32x32), ring-of-4 LDS (128KB),
// lead-3 prefetch with counted vmcnt(4) (never drains in steady state).
#define BKT 32
#define NKT (DIMK / BKT)       // 128 K-tiles
#define SLOTB 32768            // ring slot: A 16KB + B 16KB
#define LDS_TOTAL (4 * SLOTB)  // 131072
#define NGEMM ((MROW / 256) * (NCOL / 256))   // 512 GEMM blocks
#define NCVT 256                              // piggyback convert blocks (GEMM1)

typedef __attribute__((ext_vector_type(8)))  short short8;
typedef __attribute__((ext_vector_type(16))) float f32x16;

__device__ inline ushort f2bf(float f) {
  unsigned u = __float_as_uint(f);
  u += 0x7FFF + ((u >> 16) & 1);   // RNE
  return (ushort)(u >> 16);
}

__device__ inline void gload16(const void* g, void* l) {
  __builtin_amdgcn_global_load_lds(
      (const __attribute__((address_space(1))) void*)g,
      (__attribute__((address_space(3))) void*)l, 16, 0, 0);
}

__device__ inline void cvt8(const float* __restrict__ s, ushort* __restrict__ d, long i) {
  const float4* s4 = (const float4*)(s + i * 8);
  float4 a = s4[0], b = s4[1];
  ushort r[8] = {f2bf(a.x), f2bf(a.y), f2bf(a.z), f2bf(a.w),
                 f2bf(b.x), f2bf(b.y), f2bf(b.z), f2bf(b.w)};
  *(uint4*)(d + i * 8) = *(const uint4*)r;
}

// fused x + proj_w fp32->bf16 convert + coef computation (last 16 blocks)
__global__ void cvt_xpw(const float* __restrict__ x, ushort* __restrict__ xb,
                        const float* __restrict__ pw, ushort* __restrict__ pwb,
                        const float* __restrict__ mix_w, const float* __restrict__ mix_b,
                        const float* __restrict__ decay_value, const float* __restrict__ proj_b,
                        const int* __restrict__ index_p,
                        float* __restrict__ wv, float* __restrict__ cc, float* __restrict__ pb2) {
  const int CVB = 3056;                       // convert blocks; 16 coef blocks after
  if (blockIdx.x >= CVB) {
    int n = (blockIdx.x - CVB) * 256 + threadIdx.x;   // 0..4095
    if (n < NCOL) {
      int h = n >> 8;
      int idx = *index_p;
      float w  = mix_w[h * SEQL + idx];
      float bb = mix_b[h * SEQL + idx];
      float dv = fminf(fmaxf(decay_value[h], 0.9f), 1.0f);
      float decay = powf(dv, 0.125f);         // 1/DECAY_CONSTANT (=8)
      wv[n]  = w;
      cc[n]  = (h < NH / 2) ? w * decay : decay;
      pb2[n] = w * proj_b[n] + bb;
    }
    return;
  }
  const long n8x = (long)MROW * DIMK / 8;
  const long n8p = (long)NCOL * DIMK / 8;
  long stride = (long)CVB * blockDim.x;
  for (long i = (long)blockIdx.x * blockDim.x + threadIdx.x; i < n8x + n8p; i += stride) {
    if (i < n8x) cvt8(x, xb, i);
    else         cvt8(pw, pwb, i - n8x);
  }
}

// C = A(MxK)*B^T(NxK), bf16, 32x32x16 MFMA. LDS tile row = 64B (4 x 16B slots);
// swizzle: slot' = slot ^ (row&3) — conflict-free for 32-row fragment reads
// (each 32-lane half covers 4 disjoint bank-quads at 2 lanes/bank; halves
// disjoint), inverse-applied on the global staging source (linear LDS dest).
// A/B operand layout (row=lane&31, k-octet=lane>>5) and C/D layout
// (col=lane&31, row=(reg&3)+8*(reg>>2)+4*(lane>>5)) HW-verified in R5.
// 16 waves, one barrier per K-tile, counted vmcnt across barriers, ring-of-4.
// GEMM1 carries NCVT piggyback blocks converting out_w under spare HBM BW.
template <int EPI>
__global__ __launch_bounds__(1024, 4) void gemm256(
    const ushort* __restrict__ A, const ushort* __restrict__ B,
    float* __restrict__ outf, ushort* __restrict__ outh,
    const float* __restrict__ cache, const float* __restrict__ wv,
    const float* __restrict__ cc, const float* __restrict__ pb2,
    const float* __restrict__ outb,
    const float* __restrict__ owsrc, ushort* __restrict__ owdst) {
  extern __shared__ __align__(16) char smem[];

  const int bid = blockIdx.x;
  if (EPI == 1 && bid >= NGEMM) {
    // ---- piggyback: convert out_w for GEMM2 (rides GEMM1's idle HBM pipe)
    const long n8 = (long)NCOL * DIMK / 8;   // 2097152
    long stride = (long)NCVT * blockDim.x;
    for (long i = (long)(bid - NGEMM) * blockDim.x + threadIdx.x; i < n8; i += stride)
      cvt8(owsrc, owdst, i);
    return;
  }

  const int tid  = threadIdx.x;
  const int lane = tid & 63;
  const int wid  = tid >> 6;      // 0..15
  const int wr = wid >> 2;        // 0..3 (M)
  const int wc = wid & 3;         // 0..3 (N)
  const int l31 = lane & 31;
  const int lh  = lane >> 5;      // k-octet 0..1

  // XCD swizzle (512 GEMM blocks, bijective)
  const int swz = (bid & 7) * 64 + (bid >> 3);
  const int bm = swz >> 4, bn = swz & 15;   // 32 x 16 tiles
  const int m0 = bm * 256, n0 = bn * 256;

  const ushort* Ag = A + (size_t)m0 * DIMK;
  const ushort* Bg = B + (size_t)n0 * DIMK;

  // ---- precomputed LDS read byte-offsets (loop-invariant; swizzled)
  // frag(mi/ni, ks): row = base + f*32 + l31; byte = row*64 + ((ks*2+lh)^(row&3))*16
  int aoff[2][2], boff[2][2];
#pragma unroll
  for (int f = 0; f < 2; ++f)
#pragma unroll
    for (int ks = 0; ks < 2; ++ks) {
      int arow = wr * 64 + f * 32 + l31;
      aoff[f][ks] = arow * 64 + (((ks * 2 + lh) ^ (arow & 3)) << 4);
      int brow = wc * 64 + f * 32 + l31;
      boff[f][ks] = 16384 + brow * 64 + (((ks * 2 + lh) ^ (brow & 3)) << 4);
    }

  // ---- precomputed stage offsets: linear LDS dest, inverse-swizzled global src
  const int soff = tid * 16;                 // [0, 16384)
  const int srow = soff >> 6;
  const int sgo  = srow * DIMK + ((((soff >> 4) & 3) ^ (srow & 3)) << 3);

  f32x16 acc[2][2] = {};

  // prologue: stage K-tiles 0..2 into ring slots 0..2 (2 loads per thread per kt)
#pragma unroll
  for (int kt = 0; kt < 3; ++kt) {
    char* s = smem + kt * SLOTB;
    gload16(Ag + (size_t)sgo + kt * BKT, s + soff);
    gload16(Bg + (size_t)sgo + kt * BKT, s + 16384 + soff);
  }
  asm volatile("s_waitcnt vmcnt(4)" ::: "memory");   // kt0 landed
  __builtin_amdgcn_s_barrier();
  __builtin_amdgcn_sched_barrier(0);

  for (int kt = 0; kt < NKT; ++kt) {
    const char* cur = smem + (kt & 3) * SLOTB;

    short8 af[2][2], bf[2][2];
#pragma unroll
    for (int f = 0; f < 2; ++f)
#pragma unroll
      for (int ks = 0; ks < 2; ++ks)
        bf[f][ks] = *(const short8*)(cur + boff[f][ks]);
#pragma unroll
    for (int f = 0; f < 2; ++f)
#pragma unroll
      for (int ks = 0; ks < 2; ++ks)
        af[f][ks] = *(const short8*)(cur + aoff[f][ks]);

    // prefetch K-tile kt+3 into ring slot (kt+3)&3 (= (kt-1)&3, consumed last iter)
    if (kt < NKT - 3) {
      char* st = smem + ((kt + 3) & 3) * SLOTB;
      int k0 = (kt + 3) * BKT;
      gload16(Ag + (size_t)sgo + k0, st + soff);
      gload16(Bg + (size_t)sgo + k0, st + 16384 + soff);
    }

    __builtin_amdgcn_s_setprio(1);
#pragma unroll
    for (int mi = 0; mi < 2; ++mi)
#pragma unroll
      for (int ni = 0; ni < 2; ++ni) {
        acc[mi][ni] = __builtin_amdgcn_mfma_f32_32x32x16_bf16(
            af[mi][0], bf[ni][0], acc[mi][ni], 0, 0, 0);
        acc[mi][ni] = __builtin_amdgcn_mfma_f32_32x32x16_bf16(
            af[mi][1], bf[ni][1], acc[mi][ni], 0, 0, 0);
      }
    __builtin_amdgcn_s_setprio(0);

    // counted wait: guarantee kt+1 landed; deeper prefetch stays in flight
    // across the barrier (never drains to 0 in steady state).
    if (kt < NKT - 3)       asm volatile("s_waitcnt vmcnt(4)" ::: "memory");
    else if (kt == NKT - 3) asm volatile("s_waitcnt vmcnt(2)" ::: "memory");
    else if (kt == NKT - 2) asm volatile("s_waitcnt vmcnt(0)" ::: "memory");
    __builtin_amdgcn_s_barrier();
    __builtin_amdgcn_sched_barrier(0);
  }

  // ---- epilogue. C/D 32x32 map: col = lane&31, row = (reg&3)+8*(reg>>2)+4*lh
  const int colb = n0 + wc * 64 + l31;
  const int rowb = m0 + wr * 64 + lh * 4;

  float wvv[2], ccv[2], pbv[2], obv[2];
#pragma unroll
  for (int ni = 0; ni < 2; ++ni) {
    int n = colb + ni * 32;
    if (EPI == 1) { wvv[ni] = wv[n]; ccv[ni] = cc[n]; pbv[ni] = pb2[n]; }
    else          { obv[ni] = outb[n]; }
  }

#pragma unroll
  for (int mi = 0; mi < 2; ++mi) {
#pragma unroll
    for (int ni = 0; ni < 2; ++ni) {
      f32x16 v = acc[mi][ni];
      int n = colb + ni * 32;
#pragma unroll
      for (int reg = 0; reg < 16; ++reg) {
        int m = rowb + mi * 32 + (reg & 3) + ((reg >> 2) << 3);
        if (EPI == 1) {
          int h = n >> 8, kq = n & 255;
          float val = wvv[ni] * v[reg] + ccv[ni] * cache[((size_t)h * MROW + m) * HID + kq] + pbv[ni];
          outh[(size_t)m * NCOL + n] = f2bf(val);
        } else {
          outf[(size_t)m * NCOL + n] = v[reg] + obv[ni];
        }
      }
    }
  }
}

extern "C" void kernel_launch(void* const* d_in, const int* in_sizes, int n_in,
                              void* d_out, int out_size, void* d_ws, size_t ws_size,
                              hipStream_t stream) {
  const float* x      = (const float*)d_in[0];
  const float* proj_w = (const float*)d_in[1];
  const float* proj_b = (const float*)d_in[2];
  const float* mix_w  = (const float*)d_in[3];
  const float* mix_b  = (const float*)d_in[4];
  const float* decay  = (const float*)d_in[5];
  const float* cache  = (const float*)d_in[6];
  const float* out_w  = (const float*)d_in[7];
  const float* out_b  = (const float*)d_in[8];
  const int*   index  = (const int*)d_in[9];

  char* ws = (char*)d_ws;
  ushort* xb  = (ushort*)ws;                         // 64 MiB
  ushort* pwb = (ushort*)(ws + 67108864);            // 32 MiB
  ushort* owb = (ushort*)(ws + 100663296);           // 32 MiB
  ushort* hid = (ushort*)(ws + 134217728);           // 64 MiB
  float*  wv  = (float*)(ws + 201326592);
  float*  cc  = (float*)(ws + 201326592 + 16384);
  float*  pb2 = (float*)(ws + 201326592 + 32768);

  hipFuncSetAttribute((const void*)&gemm256<1>, hipFuncAttributeMaxDynamicSharedMemorySize, LDS_TOTAL);
  hipFuncSetAttribute((const void*)&gemm256<0>, hipFuncAttributeMaxDynamicSharedMemorySize, LDS_TOTAL);

  // fused x + proj_w convert + coef (ow convert rides inside GEMM1)
  hipLaunchKernelGGL(cvt_xpw, dim3(3072), dim3(256), 0, stream,
                     x, xb, proj_w, pwb,
                     mix_w, mix_b, decay, proj_b, index, wv, cc, pb2);

  // GEMM1 (+ piggyback ow-convert blocks): hidden = mix(x @ proj_w^T) -> bf16
  hipLaunchKernelGGL((gemm256<1>), dim3(NGEMM + NCVT), dim3(1024), LDS_TOTAL, stream,
                     xb, pwb, nullptr, hid, cache, wv, cc, pb2, nullptr, out_w, owb);
  // GEMM2: out = hidden @ out_w^T + out_b -> f32
  hipLaunchKernelGGL((gemm256<0>), dim3(NGEMM), dim3(1024), LDS_TOTAL, stream,
                     hid, owb, (float*)d_out, nullptr, nullptr, nullptr, nullptr, nullptr, out_b,
                     nullptr, nullptr);
}

// Round 19
// 585.460 us; speedup vs baseline: 1.3190x; 1.3190x over previous
//
#include <hip/hip_runtime.h>
#include <hip/hip_bf16.h>

// Problem constants
#define MROW 8192   // BATCH
#define DIMK 4096   // DIM (= K of both GEMMs)
#define NCOL 4096   // N_HEADS*HIDDEN = DIM
#define HID  256
#define NH   16
#define SEQL 4096

// GEMM tile geometry (best-measured, R14/R17): 256x256 tile, BK=32, 16 waves
// (4M x 4N, wave-tile 64x64), 16x16x32 MFMA, ring-of-4 LDS (4 x 32KB = 128KB),
// 1 block/CU, lead-3 prefetch with counted vmcnt(4) (never drains in steady
// state). Nine alternative schedules (barrier density, wave count, ILP
// pipelining, BK=64, phase templates, 2-tile windows, no-LDS flat, 32x32 MFMA,
// 128^2 tiles) all measured equal or worse — this is the plateau config.
#define BKT 32
#define NKT (DIMK / BKT)       // 128 K-tiles
#define SLOTB 32768            // ring slot: A 16KB + B 16KB
#define LDS_TOTAL (4 * SLOTB)  // 131072
#define NGEMM ((MROW / 256) * (NCOL / 256))   // 512 GEMM blocks
#define NCVT 256                              // piggyback convert blocks (GEMM1)

typedef __attribute__((ext_vector_type(8))) short short8;
typedef __attribute__((ext_vector_type(4))) float f32x4;

__device__ inline ushort f2bf(float f) {
  unsigned u = __float_as_uint(f);
  u += 0x7FFF + ((u >> 16) & 1);   // RNE
  return (ushort)(u >> 16);
}

__device__ inline void gload16(const void* g, void* l) {
  __builtin_amdgcn_global_load_lds(
      (const __attribute__((address_space(1))) void*)g,
      (__attribute__((address_space(3))) void*)l, 16, 0, 0);
}

__device__ inline void cvt8(const float* __restrict__ s, ushort* __restrict__ d, long i) {
  const float4* s4 = (const float4*)(s + i * 8);
  float4 a = s4[0], b = s4[1];
  ushort r[8] = {f2bf(a.x), f2bf(a.y), f2bf(a.z), f2bf(a.w),
                 f2bf(b.x), f2bf(b.y), f2bf(b.z), f2bf(b.w)};
  *(uint4*)(d + i * 8) = *(const uint4*)r;
}

// fused x + proj_w fp32->bf16 convert + coef computation (last 16 blocks)
__global__ void cvt_xpw(const float* __restrict__ x, ushort* __restrict__ xb,
                        const float* __restrict__ pw, ushort* __restrict__ pwb,
                        const float* __restrict__ mix_w, const float* __restrict__ mix_b,
                        const float* __restrict__ decay_value, const float* __restrict__ proj_b,
                        const int* __restrict__ index_p,
                        float* __restrict__ wv, float* __restrict__ cc, float* __restrict__ pb2) {
  const int CVB = 3056;                       // convert blocks; 16 coef blocks after
  if (blockIdx.x >= CVB) {
    int n = (blockIdx.x - CVB) * 256 + threadIdx.x;   // 0..4095
    if (n < NCOL) {
      int h = n >> 8;
      int idx = *index_p;
      float w  = mix_w[h * SEQL + idx];
      float bb = mix_b[h * SEQL + idx];
      float dv = fminf(fmaxf(decay_value[h], 0.9f), 1.0f);
      float decay = powf(dv, 0.125f);         // 1/DECAY_CONSTANT (=8)
      wv[n]  = w;
      cc[n]  = (h < NH / 2) ? w * decay : decay;
      pb2[n] = w * proj_b[n] + bb;
    }
    return;
  }
  const long n8x = (long)MROW * DIMK / 8;
  const long n8p = (long)NCOL * DIMK / 8;
  long stride = (long)CVB * blockDim.x;
  for (long i = (long)blockIdx.x * blockDim.x + threadIdx.x; i < n8x + n8p; i += stride) {
    if (i < n8x) cvt8(x, xb, i);
    else         cvt8(pw, pwb, i - n8x);
  }
}

// C = A(MxK)*B^T(NxK), bf16, 16x16x32 MFMA (best-measured structure).
// LDS tile row = 64B, swizzle 16B slot = c ^ ((row>>1)&3) (measured 0
// conflicts), inverse-applied on the global staging source (linear LDS dest
// for global_load_lds), forward on reads. 16 waves, one barrier per K-tile,
// counted vmcnt held across barriers (never drains in steady state), ring-of-4.
// GEMM1 carries NCVT piggyback blocks converting out_w under spare HBM BW.
template <int EPI>
__global__ __launch_bounds__(1024, 4) void gemm256(
    const ushort* __restrict__ A, const ushort* __restrict__ B,
    float* __restrict__ outf, ushort* __restrict__ outh,
    const float* __restrict__ cache, const float* __restrict__ wv,
    const float* __restrict__ cc, const float* __restrict__ pb2,
    const float* __restrict__ outb,
    const float* __restrict__ owsrc, ushort* __restrict__ owdst) {
  extern __shared__ __align__(16) char smem[];

  const int bid = blockIdx.x;
  if (EPI == 1 && bid >= NGEMM) {
    // ---- piggyback: convert out_w for GEMM2 (rides GEMM1's idle HBM pipe)
    const long n8 = (long)NCOL * DIMK / 8;   // 2097152
    long stride = (long)NCVT * blockDim.x;
    for (long i = (long)(bid - NGEMM) * blockDim.x + threadIdx.x; i < n8; i += stride)
      cvt8(owsrc, owdst, i);
    return;
  }

  const int tid  = threadIdx.x;
  const int lane = tid & 63;
  const int wid  = tid >> 6;      // 0..15
  const int wr = wid >> 2;        // 0..3 (M)
  const int wc = wid & 3;         // 0..3 (N)
  const int r16 = lane & 15;
  const int cq  = lane >> 4;      // 16B column block 0..3

  // XCD swizzle (512 GEMM blocks, bijective)
  const int swz = (bid & 7) * 64 + (bid >> 3);
  const int bm = swz >> 4, bn = swz & 15;   // 32 x 16 tiles
  const int m0 = bm * 256, n0 = bn * 256;

  const ushort* Ag = A + (size_t)m0 * DIMK;
  const ushort* Bg = B + (size_t)n0 * DIMK;

  // ---- precomputed LDS read byte-offsets (loop-invariant; swizzled)
  int aoff[4], boff[4];
#pragma unroll
  for (int i = 0; i < 4; ++i) {
    int arow = wr * 64 + i * 16 + r16;
    aoff[i] = arow * 64 + ((cq ^ ((arow >> 1) & 3)) << 4);
    int brow = wc * 64 + i * 16 + r16;
    boff[i] = 16384 + brow * 64 + ((cq ^ ((brow >> 1) & 3)) << 4);
  }

  // ---- precomputed stage offsets: linear LDS dest, inverse-swizzled global src
  const int soff = tid * 16;                 // [0, 16384)
  const int srow = soff >> 6;
  const int sgo  = srow * DIMK + ((((soff >> 4) & 3) ^ ((srow >> 1) & 3)) << 3);

  f32x4 acc[4][4] = {};

  // prologue: stage K-tiles 0..2 into ring slots 0..2 (2 loads per thread per kt)
#pragma unroll
  for (int kt = 0; kt < 3; ++kt) {
    char* s = smem + kt * SLOTB;
    gload16(Ag + (size_t)sgo + kt * BKT, s + soff);
    gload16(Bg + (size_t)sgo + kt * BKT, s + 16384 + soff);
  }
  asm volatile("s_waitcnt vmcnt(4)" ::: "memory");   // kt0 landed
  __builtin_amdgcn_s_barrier();
  __builtin_amdgcn_sched_barrier(0);

  for (int kt = 0; kt < NKT; ++kt) {
    const char* cur = smem + (kt & 3) * SLOTB;

    short8 af[4], bf[4];
#pragma unroll
    for (int i = 0; i < 4; ++i) bf[i] = *(const short8*)(cur + boff[i]);
#pragma unroll
    for (int i = 0; i < 4; ++i) af[i] = *(const short8*)(cur + aoff[i]);

    // prefetch K-tile kt+3 into ring slot (kt+3)&3 (= (kt-1)&3, consumed last iter)
    if (kt < NKT - 3) {
      char* st = smem + ((kt + 3) & 3) * SLOTB;
      int k0 = (kt + 3) * BKT;
      gload16(Ag + (size_t)sgo + k0, st + soff);
      gload16(Bg + (size_t)sgo + k0, st + 16384 + soff);
    }

    __builtin_amdgcn_s_setprio(1);
#pragma unroll
    for (int mi = 0; mi < 4; ++mi)
#pragma unroll
      for (int ni = 0; ni < 4; ++ni)
        acc[mi][ni] = __builtin_amdgcn_mfma_f32_16x16x32_bf16(af[mi], bf[ni], acc[mi][ni], 0, 0, 0);
    __builtin_amdgcn_s_setprio(0);

    // counted wait: guarantee kt+1 landed; deeper prefetch stays in flight
    // across the barrier (never drains to 0 in steady state).
    if (kt < NKT - 3)       asm volatile("s_waitcnt vmcnt(4)" ::: "memory");
    else if (kt == NKT - 3) asm volatile("s_waitcnt vmcnt(2)" ::: "memory");
    else if (kt == NKT - 2) asm volatile("s_waitcnt vmcnt(0)" ::: "memory");
    __builtin_amdgcn_s_barrier();
    __builtin_amdgcn_sched_barrier(0);
  }

  // ---- epilogue. C/D 16x16 map: col = lane&15, row = (lane>>4)*4 + reg
  const int colb = n0 + wc * 64 + r16;
  const int rowb = m0 + wr * 64 + cq * 4;

  float wvv[4], ccv[4], pbv[4], obv[4];
#pragma unroll
  for (int ni = 0; ni < 4; ++ni) {
    int n = colb + ni * 16;
    if (EPI == 1) { wvv[ni] = wv[n]; ccv[ni] = cc[n]; pbv[ni] = pb2[n]; }
    else          { obv[ni] = outb[n]; }
  }

#pragma unroll
  for (int mi = 0; mi < 4; ++mi) {
#pragma unroll
    for (int ni = 0; ni < 4; ++ni) {
      f32x4 v = acc[mi][ni];
      int n = colb + ni * 16;
#pragma unroll
      for (int r = 0; r < 4; ++r) {
        int m = rowb + mi * 16 + r;
        if (EPI == 1) {
          int h = n >> 8, kq = n & 255;
          float val = wvv[ni] * v[r] + ccv[ni] * cache[((size_t)h * MROW + m) * HID + kq] + pbv[ni];
          outh[(size_t)m * NCOL + n] = f2bf(val);
        } else {
          outf[(size_t)m * NCOL + n] = v[r] + obv[ni];
        }
      }
    }
  }
}

extern "C" void kernel_launch(void* const* d_in, const int* in_sizes, int n_in,
                              void* d_out, int out_size, void* d_ws, size_t ws_size,
                              hipStream_t stream) {
  const float* x      = (const float*)d_in[0];
  const float* proj_w = (const float*)d_in[1];
  const float* proj_b = (const float*)d_in[2];
  const float* mix_w  = (const float*)d_in[3];
  const float* mix_b  = (const float*)d_in[4];
  const float* decay  = (const float*)d_in[5];
  const float* cache  = (const float*)d_in[6];
  const float* out_w  = (const float*)d_in[7];
  const float* out_b  = (const float*)d_in[8];
  const int*   index  = (const int*)d_in[9];

  char* ws = (char*)d_ws;
  ushort* xb  = (ushort*)ws;                         // 64 MiB
  ushort* pwb = (ushort*)(ws + 67108864);            // 32 MiB
  ushort* owb = (ushort*)(ws + 100663296);           // 32 MiB
  ushort* hid = (ushort*)(ws + 134217728);           // 64 MiB
  float*  wv  = (float*)(ws + 201326592);
  float*  cc  = (float*)(ws + 201326592 + 16384);
  float*  pb2 = (float*)(ws + 201326592 + 32768);

  hipFuncSetAttribute((const void*)&gemm256<1>, hipFuncAttributeMaxDynamicSharedMemorySize, LDS_TOTAL);
  hipFuncSetAttribute((const void*)&gemm256<0>, hipFuncAttributeMaxDynamicSharedMemorySize, LDS_TOTAL);

  // fused x + proj_w convert + coef (ow convert rides inside GEMM1)
  hipLaunchKernelGGL(cvt_xpw, dim3(3072), dim3(256), 0, stream,
                     x, xb, proj_w, pwb,
                     mix_w, mix_b, decay, proj_b, index, wv, cc, pb2);

  // GEMM1 (+ piggyback ow-convert blocks): hidden = mix(x @ proj_w^T) -> bf16
  hipLaunchKernelGGL((gemm256<1>), dim3(NGEMM + NCVT), dim3(1024), LDS_TOTAL, stream,
                     xb, pwb, nullptr, hid, cache, wv, cc, pb2, nullptr, out_w, owb);
  // GEMM2: out = hidden @ out_w^T + out_b -> f32
  hipLaunchKernelGGL((gemm256<0>), dim3(NGEMM), dim3(1024), LDS_TOTAL, stream,
                     hid, owb, (float*)d_out, nullptr, nullptr, nullptr, nullptr, nullptr, out_b,
                     nullptr, nullptr);
}